// Round 1
// baseline (204.448 us; speedup 1.0000x reference)
//
#include <hip/hip_runtime.h>

// ECE: ece = sum_b | sum_{i in b} (conf_i - acc_i) | / n
// Bin: idx = ceil(c*15)-1, valid iff 0 < c <= 1 (same fp32 ops as reference;
// the validity gate is folded into the index: t<0 or t>14 routes to dump slot 15).
// Per-wave LDS histogram via ds_add_f32 atomics (replaces the 15-way
// cmp/cndmask/add register scatter: ~50 VALU insts/elem -> ~9 + 1 LDS atomic).
// 4x float4-pair unroll keeps 8 loads in flight to hide memory latency.

#define NB 15

__device__ __forceinline__ void proc4(float4 c, float4 a, float* __restrict__ h) {
    float cv[4] = {c.x, c.y, c.z, c.w};
    float av[4] = {a.x, a.y, a.z, a.w};
#pragma unroll
    for (int j = 0; j < 4; ++j) {
        float v = cv[j];
        float d = v - av[j];
        int t = (int)ceilf(v * 15.0f) - 1;          // valid => t in [0,14]
        int idx = ((unsigned)t > 14u) ? 15 : t;     // invalid -> dump slot 15
        __hip_atomic_fetch_add(&h[idx], d, __ATOMIC_RELAXED,
                               __HIP_MEMORY_SCOPE_WORKGROUP);
    }
}

__global__ __launch_bounds__(256) void ece_hist(
        const float* __restrict__ conf,
        const float* __restrict__ acc,
        float* __restrict__ partials,   // layout [NB][nblocks]
        int n4, int n, int nblocks) {
    // one 16-slot row per wave: waves 0,2 on banks 0-15, waves 1,3 on 16-31;
    // atomic conflicts only within a wave (~64 lanes over 15 addrs ~ 10 cyc).
    __shared__ float hist[4][16];
    if (threadIdx.x < 64) ((float*)hist)[threadIdx.x] = 0.0f;
    __syncthreads();

    float* h = hist[threadIdx.x >> 6];

    const float4* __restrict__ c4 = (const float4*)conf;
    const float4* __restrict__ a4 = (const float4*)acc;
    const int stride = gridDim.x * blockDim.x;
    int i = blockIdx.x * blockDim.x + threadIdx.x;

    // 4-wide: issue all 8 loads before any compute (MLP for latency hiding)
    for (; i + 3 * stride < n4; i += 4 * stride) {
        float4 c0 = c4[i];
        float4 c1 = c4[i + stride];
        float4 c2 = c4[i + 2 * stride];
        float4 c3 = c4[i + 3 * stride];
        float4 a0 = a4[i];
        float4 a1 = a4[i + stride];
        float4 a2 = a4[i + 2 * stride];
        float4 a3 = a4[i + 3 * stride];
        proc4(c0, a0, h);
        proc4(c1, a1, h);
        proc4(c2, a2, h);
        proc4(c3, a3, h);
    }
    for (; i < n4; i += stride) proc4(c4[i], a4[i], h);

    // scalar tail (n not divisible by 4) — block 0 only
    if (blockIdx.x == 0) {
        for (int k = n4 * 4 + (int)threadIdx.x; k < n; k += blockDim.x) {
            float v = conf[k];
            float d = v - acc[k];
            int t = (int)ceilf(v * 15.0f) - 1;
            int idx = ((unsigned)t > 14u) ? 15 : t;
            __hip_atomic_fetch_add(&h[idx], d, __ATOMIC_RELAXED,
                                   __HIP_MEMORY_SCOPE_WORKGROUP);
        }
    }

    __syncthreads();
    if (threadIdx.x < NB) {
        float s = hist[0][threadIdx.x] + hist[1][threadIdx.x]
                + hist[2][threadIdx.x] + hist[3][threadIdx.x];
        partials[threadIdx.x * nblocks + blockIdx.x] = s;   // no global atomics
    }
}

__global__ __launch_bounds__(960) void ece_final(
        const float* __restrict__ partials,  // [NB][nblocks]
        float* __restrict__ out, int nblocks, float inv_n) {
    __shared__ float bsum[NB];
    const int wave = threadIdx.x >> 6;   // 15 waves, one per bin
    const int lane = threadIdx.x & 63;

    float s = 0.0f;
    for (int i = lane; i < nblocks; i += 64)
        s += partials[wave * nblocks + i];   // coalesced per wave
#pragma unroll
    for (int off = 32; off > 0; off >>= 1)
        s += __shfl_down(s, off, 64);
    if (lane == 0) bsum[wave] = s;
    __syncthreads();

    if (threadIdx.x == 0) {
        float t = 0.0f;
#pragma unroll
        for (int b = 0; b < NB; ++b) t += fabsf(bsum[b]);
        out[0] = t * inv_n;
    }
}

extern "C" void kernel_launch(void* const* d_in, const int* in_sizes, int n_in,
                              void* d_out, int out_size, void* d_ws, size_t ws_size,
                              hipStream_t stream) {
    const float* conf = (const float*)d_in[0];
    const float* acc  = (const float*)d_in[1];
    float* partials   = (float*)d_ws;
    float* out        = (float*)d_out;

    const int n  = in_sizes[0];
    const int n4 = n / 4;

    int nblocks = 2048;                          // 8 blocks/CU
    while ((size_t)NB * nblocks * sizeof(float) > ws_size && nblocks > 1)
        nblocks >>= 1;
    int max_grid = (n4 + 255) / 256;
    if (nblocks > max_grid) nblocks = max_grid;
    if (nblocks < 1) nblocks = 1;

    ece_hist<<<nblocks, 256, 0, stream>>>(conf, acc, partials, n4, n, nblocks);
    ece_final<<<1, 960, 0, stream>>>(partials, out, nblocks, 1.0f / (float)n);
}

// Round 2
// 156.935 us; speedup vs baseline: 1.3028x; 1.3028x over previous
//
#include <hip/hip_runtime.h>

// ECE: ece = sum_b | sum_{i in b} (conf_i - acc_i) | / n
// Bin: idx = ceil(c*15)-1, valid iff 0 < c <= 1 (validity folded into index:
// anything outside [0,14] routes to dump slot 15, dropped at reduction).
//
// R1 lesson: LDS *atomics* on 15 shared slots serialize ~210 cyc/wave-inst
// (VALUBusy 3.7%, 91us). This version: per-THREAD private LDS rows (17-float
// stride, coprime with 32 banks) -> plain ds_read/add/ds_write RMW at ~5.8
// cyc/wave-inst, no same-address traffic. Per-CU LDS budget ~7.5us, VALU ~2us,
// both under the ~13-21us memory floor.

#define NB 15
#define STRIDE 17   // floats per thread row; 17 coprime to 32 banks

__global__ __launch_bounds__(256) void ece_hist(
        const float* __restrict__ conf,
        const float* __restrict__ acc,
        float* __restrict__ partials,   // layout [NB][nblocks]
        int n4, int n, int nblocks) {
    __shared__ float hist[256 * STRIDE];   // 17408 B -> 8+ blocks/CU
    for (int k = threadIdx.x; k < 256 * STRIDE; k += 256) hist[k] = 0.0f;
    __syncthreads();

    float* __restrict__ h = &hist[threadIdx.x * STRIDE];

    const float4* __restrict__ c4 = (const float4*)conf;
    const float4* __restrict__ a4 = (const float4*)acc;
    const int stride = gridDim.x * blockDim.x;
    int i = blockIdx.x * blockDim.x + threadIdx.x;

    // 4-wide: 8 global loads in flight before compute (MLP)
    for (; i + 3 * stride < n4; i += 4 * stride) {
        float4 c0 = c4[i];
        float4 c1 = c4[i + stride];
        float4 c2 = c4[i + 2 * stride];
        float4 c3 = c4[i + 3 * stride];
        float4 a0 = a4[i];
        float4 a1 = a4[i + stride];
        float4 a2 = a4[i + 2 * stride];
        float4 a3 = a4[i + 3 * stride];
        float cv[16] = {c0.x, c0.y, c0.z, c0.w, c1.x, c1.y, c1.z, c1.w,
                        c2.x, c2.y, c2.z, c2.w, c3.x, c3.y, c3.z, c3.w};
        float av[16] = {a0.x, a0.y, a0.z, a0.w, a1.x, a1.y, a1.z, a1.w,
                        a2.x, a2.y, a2.z, a2.w, a3.x, a3.y, a3.z, a3.w};
#pragma unroll
        for (int j = 0; j < 16; ++j) {
            float v = cv[j];
            float d = v - av[j];
            int t = (int)ceilf(v * 15.0f) - 1;       // valid => t in [0,14]
            int idx = ((unsigned)t > 14u) ? 15 : t;  // invalid -> dump slot 15
            h[idx] += d;                             // private row: plain RMW
        }
    }
    for (; i < n4; i += stride) {
        float4 c = c4[i];
        float4 a = a4[i];
        float cv[4] = {c.x, c.y, c.z, c.w};
        float av[4] = {a.x, a.y, a.z, a.w};
#pragma unroll
        for (int j = 0; j < 4; ++j) {
            float v = cv[j];
            float d = v - av[j];
            int t = (int)ceilf(v * 15.0f) - 1;
            int idx = ((unsigned)t > 14u) ? 15 : t;
            h[idx] += d;
        }
    }

    // scalar tail (n not divisible by 4) — block 0 only
    if (blockIdx.x == 0) {
        for (int k = n4 * 4 + (int)threadIdx.x; k < n; k += blockDim.x) {
            float v = conf[k];
            float d = v - acc[k];
            int t = (int)ceilf(v * 15.0f) - 1;
            int idx = ((unsigned)t > 14u) ? 15 : t;
            h[idx] += d;
        }
    }

    __syncthreads();

    // stage 1: thread t sums bin (t&15) across the 16 rows of chunk (t>>4).
    // addr = (chunk*16+r)*17 + b: per wave, banks get exactly 2 lanes (free).
    {
        const int b = threadIdx.x & 15;
        const int chunk = threadIdx.x >> 4;
        float s = 0.0f;
#pragma unroll
        for (int r = 0; r < 16; ++r)
            s += hist[(chunk * 16 + r) * STRIDE + b];
        __syncthreads();                 // reads done before rows 0..15 reused
        hist[chunk * STRIDE + b] = s;    // [chunk][bin] in rows 0..15
        __syncthreads();

        // stage 2: threads 0..14 sum across 16 chunks
        if (threadIdx.x < NB) {
            float s2 = 0.0f;
#pragma unroll
            for (int c = 0; c < 16; ++c)
                s2 += hist[c * STRIDE + threadIdx.x];
            partials[threadIdx.x * nblocks + blockIdx.x] = s2;  // no atomics
        }
    }
}

__global__ __launch_bounds__(960) void ece_final(
        const float* __restrict__ partials,  // [NB][nblocks]
        float* __restrict__ out, int nblocks, float inv_n) {
    __shared__ float bsum[NB];
    const int wave = threadIdx.x >> 6;   // 15 waves, one per bin
    const int lane = threadIdx.x & 63;

    float s = 0.0f;
    for (int i = lane; i < nblocks; i += 64)
        s += partials[wave * nblocks + i];   // coalesced per wave
#pragma unroll
    for (int off = 32; off > 0; off >>= 1)
        s += __shfl_down(s, off, 64);
    if (lane == 0) bsum[wave] = s;
    __syncthreads();

    if (threadIdx.x == 0) {
        float t = 0.0f;
#pragma unroll
        for (int b = 0; b < NB; ++b) t += fabsf(bsum[b]);
        out[0] = t * inv_n;
    }
}

extern "C" void kernel_launch(void* const* d_in, const int* in_sizes, int n_in,
                              void* d_out, int out_size, void* d_ws, size_t ws_size,
                              hipStream_t stream) {
    const float* conf = (const float*)d_in[0];
    const float* acc  = (const float*)d_in[1];
    float* partials   = (float*)d_ws;
    float* out        = (float*)d_out;

    const int n  = in_sizes[0];
    const int n4 = n / 4;

    int nblocks = 2048;                          // 8 blocks/CU
    while ((size_t)NB * nblocks * sizeof(float) > ws_size && nblocks > 1)
        nblocks >>= 1;
    int max_grid = (n4 + 255) / 256;
    if (nblocks > max_grid) nblocks = max_grid;
    if (nblocks < 1) nblocks = 1;

    ece_hist<<<nblocks, 256, 0, stream>>>(conf, acc, partials, n4, n, nblocks);
    ece_final<<<1, 960, 0, stream>>>(partials, out, nblocks, 1.0f / (float)n);
}

// Round 3
// 155.745 us; speedup vs baseline: 1.3127x; 1.0076x over previous
//
#include <hip/hip_runtime.h>

// ECE: ece = sum_b | sum_{i in b} (conf_i - acc_i) | / n
// Bin: tt = ceil(c*15), bin b matches tt == b+1 (b in 0..14). Validity is free:
// c<=0 -> tt<=0, c>1 -> tt>15, NaN -> cvt gives 0 -- none match any b.
//
// R1 lesson: LDS atomics on shared slots serialize ~210 cyc/wave-inst.
// R2 lesson: private-row LDS RMW is a serialized ds_read->wait->ds_write chain
//            (~130 cyc/elem/thread); VALU 9.5%, same 47us.
// R3: back to register bins (15 x cmp/cndmask/add = ~49 wave-insts per
// 64-elem chunk ~= 11us/CU VALU floor), with 2x float4-pair unroll for MLP
// and __launch_bounds__(256,8) to hold 8 waves/SIMD (VGPR <= 64) so the
// ~900-cycle HBM latency is hidden by issue work from other waves.

#define NB 15

__device__ __forceinline__ void proc4(float4 c, float4 a, float* __restrict__ bins) {
    float cv[4] = {c.x, c.y, c.z, c.w};
    float av[4] = {a.x, a.y, a.z, a.w};
#pragma unroll
    for (int j = 0; j < 4; ++j) {
        float v = cv[j];
        float d = v - av[j];
        int tt = (int)ceilf(v * 15.0f);   // valid => tt in 1..15
#pragma unroll
        for (int b = 0; b < NB; ++b)
            bins[b] += (tt == b + 1) ? d : 0.0f;   // b+1 is an inline const
    }
}

__global__ __launch_bounds__(256, 8) void ece_hist(
        const float* __restrict__ conf,
        const float* __restrict__ acc,
        float* __restrict__ partials,   // layout [NB][nblocks]
        int n4, int n, int nblocks) {
    float bins[NB];
#pragma unroll
    for (int b = 0; b < NB; ++b) bins[b] = 0.0f;

    const float4* __restrict__ c4 = (const float4*)conf;
    const float4* __restrict__ a4 = (const float4*)acc;
    const int stride = gridDim.x * blockDim.x;
    int i = blockIdx.x * blockDim.x + threadIdx.x;

    // 2-wide: 4 float4 loads (4 KB/wave) in flight before any compute
    for (; i + stride < n4; i += 2 * stride) {
        float4 c0 = c4[i];
        float4 c1 = c4[i + stride];
        float4 a0 = a4[i];
        float4 a1 = a4[i + stride];
        proc4(c0, a0, bins);
        proc4(c1, a1, bins);
    }
    for (; i < n4; i += stride) proc4(c4[i], a4[i], bins);

    // scalar tail (n not divisible by 4) — block 0 only
    if (blockIdx.x == 0) {
        for (int k = n4 * 4 + (int)threadIdx.x; k < n; k += blockDim.x) {
            float v = conf[k];
            float d = v - acc[k];
            int tt = (int)ceilf(v * 15.0f);
#pragma unroll
            for (int b = 0; b < NB; ++b)
                bins[b] += (tt == b + 1) ? d : 0.0f;
        }
    }

    // wave reduction (64 lanes)
#pragma unroll
    for (int b = 0; b < NB; ++b) {
        float v = bins[b];
#pragma unroll
        for (int off = 32; off > 0; off >>= 1)
            v += __shfl_down(v, off, 64);
        bins[b] = v;
    }

    __shared__ float wsum[4][NB];       // 256 threads = 4 waves
    const int wave = threadIdx.x >> 6;
    const int lane = threadIdx.x & 63;
    if (lane == 0) {
#pragma unroll
        for (int b = 0; b < NB; ++b) wsum[wave][b] = bins[b];
    }
    __syncthreads();

    if (threadIdx.x < NB) {
        float s = wsum[0][threadIdx.x] + wsum[1][threadIdx.x]
                + wsum[2][threadIdx.x] + wsum[3][threadIdx.x];
        partials[threadIdx.x * nblocks + blockIdx.x] = s;   // no atomics
    }
}

__global__ __launch_bounds__(960) void ece_final(
        const float* __restrict__ partials,  // [NB][nblocks]
        float* __restrict__ out, int nblocks, float inv_n) {
    __shared__ float bsum[NB];
    const int wave = threadIdx.x >> 6;   // 15 waves, one per bin
    const int lane = threadIdx.x & 63;

    float s = 0.0f;
    for (int i = lane; i < nblocks; i += 64)
        s += partials[wave * nblocks + i];   // coalesced per wave
#pragma unroll
    for (int off = 32; off > 0; off >>= 1)
        s += __shfl_down(s, off, 64);
    if (lane == 0) bsum[wave] = s;
    __syncthreads();

    if (threadIdx.x == 0) {
        float t = 0.0f;
#pragma unroll
        for (int b = 0; b < NB; ++b) t += fabsf(bsum[b]);
        out[0] = t * inv_n;
    }
}

extern "C" void kernel_launch(void* const* d_in, const int* in_sizes, int n_in,
                              void* d_out, int out_size, void* d_ws, size_t ws_size,
                              hipStream_t stream) {
    const float* conf = (const float*)d_in[0];
    const float* acc  = (const float*)d_in[1];
    float* partials   = (float*)d_ws;
    float* out        = (float*)d_out;

    const int n  = in_sizes[0];
    const int n4 = n / 4;

    int nblocks = 2048;                          // 8 blocks/CU
    while ((size_t)NB * nblocks * sizeof(float) > ws_size && nblocks > 1)
        nblocks >>= 1;
    int max_grid = (n4 + 255) / 256;
    if (nblocks > max_grid) nblocks = max_grid;
    if (nblocks < 1) nblocks = 1;

    ece_hist<<<nblocks, 256, 0, stream>>>(conf, acc, partials, n4, n, nblocks);
    ece_final<<<1, 960, 0, stream>>>(partials, out, nblocks, 1.0f / (float)n);
}